// Round 2
// baseline (638.602 us; speedup 1.0000x reference)
//
#include <hip/hip_runtime.h>
#include <stdint.h>

// R2: inputs/outputs are FP32 (reference is jnp.float32; R1's NaN absmax =
// fp32 bits read as bf16). Convert to bf16 in workspace, run bf16-MFMA
// pipeline, emit fp32 from the final GEMM. 2%-of-max threshold absorbs
// bf16 rounding.

typedef unsigned short u16;
typedef short bf16x8 __attribute__((ext_vector_type(8)));
typedef float f32x4 __attribute__((ext_vector_type(4)));

#define D_MODEL 2048
#define NUM_HEADS 32
#define HEAD_DIM 64
#define KV_DIM 512
#define SEQ 2048
#define MTOT 4096

static __device__ __forceinline__ u16 f2bf(float f){
  uint32_t u = __builtin_bit_cast(uint32_t, f);
  u += 0x7FFFu + ((u >> 16) & 1u);
  return (u16)(u >> 16);
}

static __device__ __forceinline__ void gload16(const u16* g, u16* l){
  __builtin_amdgcn_global_load_lds(
      (__attribute__((address_space(1))) uint32_t*)(uintptr_t)g,
      (__attribute__((address_space(3))) uint32_t*)l,
      16, 0, 0);
}

// fp32 -> bf16, 8 elements/thread. n must be divisible by 2048 (all ours are).
__global__ __launch_bounds__(256)
void cvt_bf16(const float* __restrict__ in, u16* __restrict__ out, int n){
  const int i = (blockIdx.x * 256 + threadIdx.x) * 8;
  if (i >= n) return;
  float4 a = *(const float4*)(in + i);
  float4 b = *(const float4*)(in + i + 4);
  union { u16 h[8]; uint4 v; } t;
  t.h[0]=f2bf(a.x); t.h[1]=f2bf(a.y); t.h[2]=f2bf(a.z); t.h[3]=f2bf(a.w);
  t.h[4]=f2bf(b.x); t.h[5]=f2bf(b.y); t.h[6]=f2bf(b.z); t.h[7]=f2bf(b.w);
  *(uint4*)(out + i) = t.v;
}

// C[M,N] = A[M,K] @ B[N,K]^T, bf16 in, fp32 accum, bf16 or fp32 out.
template <bool F32OUT>
__global__ __launch_bounds__(256)
void gemm_bt(const u16* __restrict__ A, const u16* __restrict__ B,
             void* __restrict__ Cv, int M, int N, int K){
  constexpr int BM = 128, BN = 128, BK = 32;
  __shared__ __attribute__((aligned(16))) u16 As[BM*BK];
  __shared__ __attribute__((aligned(16))) u16 Bs[BN*BK];
  const int tid  = threadIdx.x;
  const int wave = tid >> 6, lane = tid & 63;
  const int quad = lane >> 4, l16 = lane & 15;
  const int wrow = wave >> 1, wcol = wave & 1;
  const int m0 = blockIdx.y * BM, n0 = blockIdx.x * BN;
  const int srow = lane >> 2, scol = (lane & 3) * 8;

  const f32x4 zero = {0.f, 0.f, 0.f, 0.f};
  f32x4 acc[4][4];
#pragma unroll
  for (int i = 0; i < 4; i++)
#pragma unroll
    for (int j = 0; j < 4; j++) acc[i][j] = zero;

  for (int k0 = 0; k0 < K; k0 += BK){
#pragma unroll
    for (int t = 0; t < 2; t++){
      const int chunk = wave + t*4;
      gload16(A + (size_t)(m0 + chunk*16 + srow)*K + k0 + scol, As + chunk*16*BK);
      gload16(B + (size_t)(n0 + chunk*16 + srow)*K + k0 + scol, Bs + chunk*16*BK);
    }
    __syncthreads();
    bf16x8 af[4], bfr[4];
#pragma unroll
    for (int mi = 0; mi < 4; mi++)
      af[mi] = *(const bf16x8*)(As + (wrow*64 + mi*16 + l16)*BK + quad*8);
#pragma unroll
    for (int ni = 0; ni < 4; ni++)
      bfr[ni] = *(const bf16x8*)(Bs + (wcol*64 + ni*16 + l16)*BK + quad*8);
#pragma unroll
    for (int mi = 0; mi < 4; mi++)
#pragma unroll
      for (int ni = 0; ni < 4; ni++)
        acc[mi][ni] = __builtin_amdgcn_mfma_f32_16x16x32_bf16(af[mi], bfr[ni], acc[mi][ni], 0, 0, 0);
    __syncthreads();
  }
#pragma unroll
  for (int mi = 0; mi < 4; mi++)
#pragma unroll
    for (int ni = 0; ni < 4; ni++){
      const int col = n0 + wcol*64 + ni*16 + l16;
#pragma unroll
      for (int r = 0; r < 4; r++){
        const int row = m0 + wrow*64 + mi*16 + quad*4 + r;
        if constexpr (F32OUT)
          ((float*)Cv)[(size_t)row*N + col] = acc[mi][ni][r];
        else
          ((u16*)Cv)[(size_t)row*N + col] = f2bf(acc[mi][ni][r]);
      }
    }
}

// Flash attention, causal, GQA group=4. One block = (b, h, 64-row q-tile).
__global__ __launch_bounds__(256)
void attn(const u16* __restrict__ Q, const u16* __restrict__ Kp,
          const u16* __restrict__ Vp, u16* __restrict__ O){
  constexpr int KP = 72;  // pitch: 144B = 9*16B, 16B-aligned rows, no pow2 stride
  __shared__ __attribute__((aligned(16))) u16 Ks[64*KP];
  __shared__ __attribute__((aligned(16))) u16 Vt[64*KP];   // Vt[d][n]
  __shared__ __attribute__((aligned(16))) u16 Ps[4*16*KP]; // wave-private strips
  const int tid = threadIdx.x;
  const int wave = tid >> 6, lane = tid & 63, quad = lane >> 4, l16 = lane & 15;
  const int qt = blockIdx.x, h = blockIdx.y, b = blockIdx.z;
  const int hk = h >> 2;
  const size_t rb = (size_t)b * SEQ;

  bf16x8 qf[2];
  {
    const u16* qp = Q + (rb + qt*64 + wave*16 + l16)*D_MODEL + h*HEAD_DIM;
    qf[0] = *(const bf16x8*)(qp + quad*8);
    qf[1] = *(const bf16x8*)(qp + 32 + quad*8);
  }
  const f32x4 zero = {0.f, 0.f, 0.f, 0.f};
  f32x4 oacc[4];
#pragma unroll
  for (int i = 0; i < 4; i++) oacc[i] = zero;
  float m_i[4] = {-INFINITY, -INFINITY, -INFINITY, -INFINITY};
  float l_i[4] = {0.f, 0.f, 0.f, 0.f};
  u16* Pw = Ps + wave*16*KP;

  for (int j = 0; j <= qt; ++j){
    {
      const int r = tid >> 2, s = tid & 3;
      const u16* kg = Kp + (rb + j*64 + r)*KV_DIM + hk*HEAD_DIM;
      *(uint4*)(Ks + r*KP + s*8)     = *(const uint4*)(kg + s*8);
      *(uint4*)(Ks + r*KP + (s+4)*8) = *(const uint4*)(kg + (s+4)*8);
    }
#pragma unroll
    for (int t = 0; t < 2; t++){
      const int task = tid + t*256;
      const int n = task >> 3, ds = task & 7;
      const u16* vg = Vp + (rb + j*64 + n)*KV_DIM + hk*HEAD_DIM + ds*8;
      alignas(16) u16 tmp[8];
      *(uint4*)tmp = *(const uint4*)vg;
#pragma unroll
      for (int e = 0; e < 8; e++) Vt[(ds*8 + e)*KP + n] = tmp[e];
    }
    __syncthreads();

    f32x4 st[4];
#pragma unroll
    for (int ni = 0; ni < 4; ni++){
      f32x4 s = zero;
#pragma unroll
      for (int ss = 0; ss < 2; ss++){
        bf16x8 kf = *(const bf16x8*)(Ks + (ni*16 + l16)*KP + ss*32 + quad*8);
        s = __builtin_amdgcn_mfma_f32_16x16x32_bf16(qf[ss], kf, s, 0, 0, 0);
      }
#pragma unroll
      for (int r = 0; r < 4; r++) st[ni][r] = s[r] * 0.125f;
    }
    if (j == qt){
#pragma unroll
      for (int ni = 0; ni < 4; ni++){
        const int col = ni*16 + l16;
#pragma unroll
        for (int r = 0; r < 4; r++)
          if (col > wave*16 + quad*4 + r) st[ni][r] = -INFINITY;
      }
    }
    float alpha[4];
#pragma unroll
    for (int r = 0; r < 4; r++){
      float mx = fmaxf(fmaxf(st[0][r], st[1][r]), fmaxf(st[2][r], st[3][r]));
      mx = fmaxf(mx, __shfl_xor(mx, 1));
      mx = fmaxf(mx, __shfl_xor(mx, 2));
      mx = fmaxf(mx, __shfl_xor(mx, 4));
      mx = fmaxf(mx, __shfl_xor(mx, 8));
      const float mn = fmaxf(m_i[r], mx);
      alpha[r] = __expf(m_i[r] - mn);
      float ps = 0.f;
#pragma unroll
      for (int ni = 0; ni < 4; ni++){
        const float p = __expf(st[ni][r] - mn);
        st[ni][r] = p;
        ps += p;
      }
      ps += __shfl_xor(ps, 1);
      ps += __shfl_xor(ps, 2);
      ps += __shfl_xor(ps, 4);
      ps += __shfl_xor(ps, 8);
      l_i[r] = l_i[r]*alpha[r] + ps;
      m_i[r] = mn;
    }
#pragma unroll
    for (int ci = 0; ci < 4; ci++)
#pragma unroll
      for (int r = 0; r < 4; r++) oacc[ci][r] *= alpha[r];
#pragma unroll
    for (int ni = 0; ni < 4; ni++)
#pragma unroll
      for (int r = 0; r < 4; r++)
        Pw[(quad*4 + r)*KP + ni*16 + l16] = f2bf(st[ni][r]);
    __asm__ volatile("s_waitcnt lgkmcnt(0)" ::: "memory");
#pragma unroll
    for (int ss = 0; ss < 2; ss++){
      bf16x8 pf = *(const bf16x8*)(Pw + l16*KP + ss*32 + quad*8);
#pragma unroll
      for (int ci = 0; ci < 4; ci++){
        bf16x8 vf = *(const bf16x8*)(Vt + (ci*16 + l16)*KP + ss*32 + quad*8);
        oacc[ci] = __builtin_amdgcn_mfma_f32_16x16x32_bf16(pf, vf, oacc[ci], 0, 0, 0);
      }
    }
    __syncthreads();
  }
#pragma unroll
  for (int ci = 0; ci < 4; ci++)
#pragma unroll
    for (int r = 0; r < 4; r++){
      const size_t row = rb + qt*64 + wave*16 + quad*4 + r;
      O[row*D_MODEL + h*HEAD_DIM + ci*16 + l16] = f2bf(oacc[ci][r] / l_i[r]);
    }
}

extern "C" void kernel_launch(void* const* d_in, const int* in_sizes, int n_in,
                              void* d_out, int out_size, void* d_ws, size_t ws_size,
                              hipStream_t stream){
  const float* x  = (const float*)d_in[0];
  const float* Wq = (const float*)d_in[1];
  const float* Wk = (const float*)d_in[2];
  const float* Wv = (const float*)d_in[3];
  const float* Wo = (const float*)d_in[4];
  float* out = (float*)d_out;

  // workspace (u16 units): xb | Qb | Kb | Vb | Wslot ; attn out aliases xb.
  u16* xb = (u16*)d_ws;                               // 8,388,608
  u16* Qb = xb + (size_t)MTOT*D_MODEL;                // 8,388,608
  u16* Kb = Qb + (size_t)MTOT*D_MODEL;                // 2,097,152
  u16* Vb = Kb + (size_t)MTOT*KV_DIM;                 // 2,097,152
  u16* Wb = Vb + (size_t)MTOT*KV_DIM;                 // 4,194,304 (slot)

  const int nx = MTOT*D_MODEL;          // 8,388,608
  const int nwq = D_MODEL*D_MODEL;      // 4,194,304
  const int nwk = KV_DIM*D_MODEL;       // 1,048,576

  cvt_bf16<<<nx/(8*256), 256, 0, stream>>>(x, xb, nx);
  cvt_bf16<<<nwq/(8*256), 256, 0, stream>>>(Wq, Wb, nwq);
  gemm_bt<false><<<dim3(D_MODEL/128, MTOT/128), 256, 0, stream>>>(xb, Wb, Qb, MTOT, D_MODEL, D_MODEL);
  cvt_bf16<<<nwk/(8*256), 256, 0, stream>>>(Wk, Wb, nwk);
  gemm_bt<false><<<dim3(KV_DIM/128, MTOT/128), 256, 0, stream>>>(xb, Wb, Kb, MTOT, KV_DIM, D_MODEL);
  cvt_bf16<<<nwk/(8*256), 256, 0, stream>>>(Wv, Wb, nwk);
  gemm_bt<false><<<dim3(KV_DIM/128, MTOT/128), 256, 0, stream>>>(xb, Wb, Vb, MTOT, KV_DIM, D_MODEL);
  attn<<<dim3(SEQ/64, NUM_HEADS, 2), 256, 0, stream>>>(Qb, Kb, Vb, xb);  // xb now attn-out
  cvt_bf16<<<nwq/(8*256), 256, 0, stream>>>(Wo, Wb, nwq);
  gemm_bt<true><<<dim3(D_MODEL/128, MTOT/128), 256, 0, stream>>>(xb, Wb, (void*)out, MTOT, D_MODEL, D_MODEL);
}

// Round 5
// 562.817 us; speedup vs baseline: 1.1347x; 1.1347x over previous
//
#include <hip/hip_runtime.h>
#include <stdint.h>

// R5: bisect arm 2. R3/R4 failed identically => bug is in the restructure,
// not LDS swizzle. This round: KEEP fused QKV GEMM + d_out scratch,
// DROP vtrans + BN=128 attn. attn is R2's passing version verbatim, with
// row strides parameterized (qs=ks=3072) to read the fused QKV buffer.

typedef unsigned short u16;
typedef short bf16x8 __attribute__((ext_vector_type(8)));
typedef float f32x4 __attribute__((ext_vector_type(4)));

#define D_MODEL 2048
#define QKV_DIM 3072
#define NUM_HEADS 32
#define HEAD_DIM 64
#define SEQ 2048
#define MTOT 4096

static __device__ __forceinline__ u16 f2bf(float f){
  uint32_t u = __builtin_bit_cast(uint32_t, f);
  u += 0x7FFFu + ((u >> 16) & 1u);
  return (u16)(u >> 16);
}

static __device__ __forceinline__ void gload16(const u16* g, u16* l){
  __builtin_amdgcn_global_load_lds(
      (__attribute__((address_space(1))) uint32_t*)(uintptr_t)g,
      (__attribute__((address_space(3))) uint32_t*)l,
      16, 0, 0);
}

__global__ __launch_bounds__(256)
void cvt_bf16(const float* __restrict__ in, u16* __restrict__ out, int n){
  const int i = (blockIdx.x * 256 + threadIdx.x) * 8;
  if (i >= n) return;
  float4 a = *(const float4*)(in + i);
  float4 b = *(const float4*)(in + i + 4);
  union { u16 h[8]; uint4 v; } t;
  t.h[0]=f2bf(a.x); t.h[1]=f2bf(a.y); t.h[2]=f2bf(a.z); t.h[3]=f2bf(a.w);
  t.h[4]=f2bf(b.x); t.h[5]=f2bf(b.y); t.h[6]=f2bf(b.z); t.h[7]=f2bf(b.w);
  *(uint4*)(out + i) = t.v;
}

// C[M,N] = A[M,K] @ B[N,K]^T (m97 structure, unchanged from R2).
template <bool F32OUT>
__global__ __launch_bounds__(256)
void gemm_bt(const u16* __restrict__ A, const u16* __restrict__ B,
             void* __restrict__ Cv, int M, int N, int K){
  constexpr int BK = 32;
  __shared__ __attribute__((aligned(16))) u16 As[128*BK];
  __shared__ __attribute__((aligned(16))) u16 Bs[128*BK];
  const int tid  = threadIdx.x;
  const int wave = tid >> 6, lane = tid & 63;
  const int quad = lane >> 4, l16 = lane & 15;
  const int wrow = wave >> 1, wcol = wave & 1;
  const int m0 = blockIdx.y * 128, n0 = blockIdx.x * 128;
  const int srow = lane >> 2, scol = (lane & 3) * 8;

  const f32x4 zero = {0.f, 0.f, 0.f, 0.f};
  f32x4 acc[4][4];
#pragma unroll
  for (int i = 0; i < 4; i++)
#pragma unroll
    for (int j = 0; j < 4; j++) acc[i][j] = zero;

  for (int k0 = 0; k0 < K; k0 += BK){
#pragma unroll
    for (int t = 0; t < 2; t++){
      const int chunk = wave + t*4;
      gload16(A + (size_t)(m0 + chunk*16 + srow)*K + k0 + scol, As + chunk*16*BK);
      gload16(B + (size_t)(n0 + chunk*16 + srow)*K + k0 + scol, Bs + chunk*16*BK);
    }
    __syncthreads();
    bf16x8 af[4], bfr[4];
#pragma unroll
    for (int mi = 0; mi < 4; mi++)
      af[mi] = *(const bf16x8*)(As + (wrow*64 + mi*16 + l16)*BK + quad*8);
#pragma unroll
    for (int ni = 0; ni < 4; ni++)
      bfr[ni] = *(const bf16x8*)(Bs + (wcol*64 + ni*16 + l16)*BK + quad*8);
#pragma unroll
    for (int mi = 0; mi < 4; mi++)
#pragma unroll
      for (int ni = 0; ni < 4; ni++)
        acc[mi][ni] = __builtin_amdgcn_mfma_f32_16x16x32_bf16(af[mi], bfr[ni], acc[mi][ni], 0, 0, 0);
    __syncthreads();
  }
#pragma unroll
  for (int mi = 0; mi < 4; mi++)
#pragma unroll
    for (int ni = 0; ni < 4; ni++){
      const int col = n0 + wcol*64 + ni*16 + l16;
#pragma unroll
      for (int r = 0; r < 4; r++){
        const int row = m0 + wrow*64 + mi*16 + quad*4 + r;
        if constexpr (F32OUT)
          ((float*)Cv)[(size_t)row*N + col] = acc[mi][ni][r];
        else
          ((u16*)Cv)[(size_t)row*N + col] = f2bf(acc[mi][ni][r]);
      }
    }
}

// R2's attn VERBATIM (passed at R2), with row strides qs/ks parameterized.
// Flash attention, causal, GQA group=4. One block = (b, h, 64-row q-tile).
__global__ __launch_bounds__(256)
void attn(const u16* __restrict__ Q, const u16* __restrict__ Kp,
          const u16* __restrict__ Vp, u16* __restrict__ O, int qs, int ks){
  constexpr int KP = 72;
  __shared__ __attribute__((aligned(16))) u16 Ks[64*KP];
  __shared__ __attribute__((aligned(16))) u16 Vt[64*KP];
  __shared__ __attribute__((aligned(16))) u16 Ps[4*16*KP];
  const int tid = threadIdx.x;
  const int wave = tid >> 6, lane = tid & 63, quad = lane >> 4, l16 = lane & 15;
  const int qt = blockIdx.x, h = blockIdx.y, b = blockIdx.z;
  const int hk = h >> 2;
  const size_t rb = (size_t)b * SEQ;

  bf16x8 qf[2];
  {
    const u16* qp = Q + (rb + qt*64 + wave*16 + l16)*qs + h*HEAD_DIM;
    qf[0] = *(const bf16x8*)(qp + quad*8);
    qf[1] = *(const bf16x8*)(qp + 32 + quad*8);
  }
  const f32x4 zero = {0.f, 0.f, 0.f, 0.f};
  f32x4 oacc[4];
#pragma unroll
  for (int i = 0; i < 4; i++) oacc[i] = zero;
  float m_i[4] = {-INFINITY, -INFINITY, -INFINITY, -INFINITY};
  float l_i[4] = {0.f, 0.f, 0.f, 0.f};
  u16* Pw = Ps + wave*16*KP;

  for (int j = 0; j <= qt; ++j){
    {
      const int r = tid >> 2, s = tid & 3;
      const u16* kg = Kp + (rb + j*64 + r)*ks + hk*HEAD_DIM;
      *(uint4*)(Ks + r*KP + s*8)     = *(const uint4*)(kg + s*8);
      *(uint4*)(Ks + r*KP + (s+4)*8) = *(const uint4*)(kg + (s+4)*8);
    }
#pragma unroll
    for (int t = 0; t < 2; t++){
      const int task = tid + t*256;
      const int n = task >> 3, ds = task & 7;
      const u16* vg = Vp + (rb + j*64 + n)*ks + hk*HEAD_DIM + ds*8;
      alignas(16) u16 tmp[8];
      *(uint4*)tmp = *(const uint4*)vg;
#pragma unroll
      for (int e = 0; e < 8; e++) Vt[(ds*8 + e)*KP + n] = tmp[e];
    }
    __syncthreads();

    f32x4 st[4];
#pragma unroll
    for (int ni = 0; ni < 4; ni++){
      f32x4 s = zero;
#pragma unroll
      for (int ss = 0; ss < 2; ss++){
        bf16x8 kf = *(const bf16x8*)(Ks + (ni*16 + l16)*KP + ss*32 + quad*8);
        s = __builtin_amdgcn_mfma_f32_16x16x32_bf16(qf[ss], kf, s, 0, 0, 0);
      }
#pragma unroll
      for (int r = 0; r < 4; r++) st[ni][r] = s[r] * 0.125f;
    }
    if (j == qt){
#pragma unroll
      for (int ni = 0; ni < 4; ni++){
        const int col = ni*16 + l16;
#pragma unroll
        for (int r = 0; r < 4; r++)
          if (col > wave*16 + quad*4 + r) st[ni][r] = -INFINITY;
      }
    }
    float alpha[4];
#pragma unroll
    for (int r = 0; r < 4; r++){
      float mx = fmaxf(fmaxf(st[0][r], st[1][r]), fmaxf(st[2][r], st[3][r]));
      mx = fmaxf(mx, __shfl_xor(mx, 1));
      mx = fmaxf(mx, __shfl_xor(mx, 2));
      mx = fmaxf(mx, __shfl_xor(mx, 4));
      mx = fmaxf(mx, __shfl_xor(mx, 8));
      const float mn = fmaxf(m_i[r], mx);
      alpha[r] = __expf(m_i[r] - mn);
      float ps = 0.f;
#pragma unroll
      for (int ni = 0; ni < 4; ni++){
        const float p = __expf(st[ni][r] - mn);
        st[ni][r] = p;
        ps += p;
      }
      ps += __shfl_xor(ps, 1);
      ps += __shfl_xor(ps, 2);
      ps += __shfl_xor(ps, 4);
      ps += __shfl_xor(ps, 8);
      l_i[r] = l_i[r]*alpha[r] + ps;
      m_i[r] = mn;
    }
#pragma unroll
    for (int ci = 0; ci < 4; ci++)
#pragma unroll
      for (int r = 0; r < 4; r++) oacc[ci][r] *= alpha[r];
#pragma unroll
    for (int ni = 0; ni < 4; ni++)
#pragma unroll
      for (int r = 0; r < 4; r++)
        Pw[(quad*4 + r)*KP + ni*16 + l16] = f2bf(st[ni][r]);
    __asm__ volatile("s_waitcnt lgkmcnt(0)" ::: "memory");
#pragma unroll
    for (int ss = 0; ss < 2; ss++){
      bf16x8 pf = *(const bf16x8*)(Pw + l16*KP + ss*32 + quad*8);
#pragma unroll
      for (int ci = 0; ci < 4; ci++){
        bf16x8 vf = *(const bf16x8*)(Vt + (ci*16 + l16)*KP + ss*32 + quad*8);
        oacc[ci] = __builtin_amdgcn_mfma_f32_16x16x32_bf16(pf, vf, oacc[ci], 0, 0, 0);
      }
    }
    __syncthreads();
  }
#pragma unroll
  for (int ci = 0; ci < 4; ci++)
#pragma unroll
    for (int r = 0; r < 4; r++){
      const size_t row = rb + qt*64 + wave*16 + quad*4 + r;
      O[row*D_MODEL + h*HEAD_DIM + ci*16 + l16] = f2bf(oacc[ci][r] / l_i[r]);
    }
}

extern "C" void kernel_launch(void* const* d_in, const int* in_sizes, int n_in,
                              void* d_out, int out_size, void* d_ws, size_t ws_size,
                              hipStream_t stream){
  const float* x  = (const float*)d_in[0];
  const float* Wq = (const float*)d_in[1];
  const float* Wk = (const float*)d_in[2];
  const float* Wv = (const float*)d_in[3];
  const float* Wo = (const float*)d_in[4];
  float* out = (float*)d_out;

  u16* xb   = (u16*)d_ws;                 // x / later attn-out, [4096,2048]
  u16* Wb   = xb + (size_t)MTOT*D_MODEL;  // fused weights [3072,2048]
  u16* QKVb = (u16*)d_out;                // QKV scratch [4096,3072] bf16

  const int nx  = MTOT*D_MODEL;
  const int nwq = D_MODEL*D_MODEL;
  const int nwk = 512*D_MODEL;

  cvt_bf16<<<nx/2048, 256, 0, stream>>>(x, xb, nx);
  cvt_bf16<<<nwq/2048, 256, 0, stream>>>(Wq, Wb, nwq);
  cvt_bf16<<<nwk/2048, 256, 0, stream>>>(Wk, Wb + (size_t)D_MODEL*D_MODEL, nwk);
  cvt_bf16<<<nwk/2048, 256, 0, stream>>>(Wv, Wb + (size_t)2560*D_MODEL, nwk);
  gemm_bt<false><<<dim3(QKV_DIM/128, MTOT/128), 256, 0, stream>>>(xb, Wb, QKVb, MTOT, QKV_DIM, D_MODEL);
  attn<<<dim3(SEQ/64, NUM_HEADS, 2), 256, 0, stream>>>(
      QKVb, QKVb + D_MODEL, QKVb + 2560, xb, QKV_DIM, QKV_DIM);
  cvt_bf16<<<nwq/2048, 256, 0, stream>>>(Wo, Wb, nwq);
  gemm_bt<true><<<dim3(D_MODEL/128, MTOT/128), 256, 0, stream>>>(xb, Wb, (void*)out, MTOT, D_MODEL, D_MODEL);
}

// Round 6
// 473.531 us; speedup vs baseline: 1.3486x; 1.1886x over previous
//
#include <hip/hip_runtime.h>
#include <stdint.h>

// R6: final bisect arm + perf fix. Base = R5 (passing) verbatim. ONE change:
// V is pre-transposed to a dedicated global buffer (vtrans) and attn stages
// V^T with uint4 reads/writes mirroring the K-staging pattern — replacing
// the 16-way-bank-conflict scalar scatter (4.2e7 conflict cycles in R5).

typedef unsigned short u16;
typedef short bf16x8 __attribute__((ext_vector_type(8)));
typedef float f32x4 __attribute__((ext_vector_type(4)));

#define D_MODEL 2048
#define QKV_DIM 3072
#define NUM_HEADS 32
#define HEAD_DIM 64
#define SEQ 2048
#define MTOT 4096

static __device__ __forceinline__ u16 f2bf(float f){
  uint32_t u = __builtin_bit_cast(uint32_t, f);
  u += 0x7FFFu + ((u >> 16) & 1u);
  return (u16)(u >> 16);
}

static __device__ __forceinline__ void gload16(const u16* g, u16* l){
  __builtin_amdgcn_global_load_lds(
      (__attribute__((address_space(1))) uint32_t*)(uintptr_t)g,
      (__attribute__((address_space(3))) uint32_t*)l,
      16, 0, 0);
}

__global__ __launch_bounds__(256)
void cvt_bf16(const float* __restrict__ in, u16* __restrict__ out, int n){
  const int i = (blockIdx.x * 256 + threadIdx.x) * 8;
  if (i >= n) return;
  float4 a = *(const float4*)(in + i);
  float4 b = *(const float4*)(in + i + 4);
  union { u16 h[8]; uint4 v; } t;
  t.h[0]=f2bf(a.x); t.h[1]=f2bf(a.y); t.h[2]=f2bf(a.z); t.h[3]=f2bf(a.w);
  t.h[4]=f2bf(b.x); t.h[5]=f2bf(b.y); t.h[6]=f2bf(b.z); t.h[7]=f2bf(b.w);
  *(uint4*)(out + i) = t.v;
}

// C[M,N] = A[M,K] @ B[N,K]^T (m97 structure, unchanged).
template <bool F32OUT>
__global__ __launch_bounds__(256)
void gemm_bt(const u16* __restrict__ A, const u16* __restrict__ B,
             void* __restrict__ Cv, int M, int N, int K){
  constexpr int BK = 32;
  __shared__ __attribute__((aligned(16))) u16 As[128*BK];
  __shared__ __attribute__((aligned(16))) u16 Bs[128*BK];
  const int tid  = threadIdx.x;
  const int wave = tid >> 6, lane = tid & 63;
  const int quad = lane >> 4, l16 = lane & 15;
  const int wrow = wave >> 1, wcol = wave & 1;
  const int m0 = blockIdx.y * 128, n0 = blockIdx.x * 128;
  const int srow = lane >> 2, scol = (lane & 3) * 8;

  const f32x4 zero = {0.f, 0.f, 0.f, 0.f};
  f32x4 acc[4][4];
#pragma unroll
  for (int i = 0; i < 4; i++)
#pragma unroll
    for (int j = 0; j < 4; j++) acc[i][j] = zero;

  for (int k0 = 0; k0 < K; k0 += BK){
#pragma unroll
    for (int t = 0; t < 2; t++){
      const int chunk = wave + t*4;
      gload16(A + (size_t)(m0 + chunk*16 + srow)*K + k0 + scol, As + chunk*16*BK);
      gload16(B + (size_t)(n0 + chunk*16 + srow)*K + k0 + scol, Bs + chunk*16*BK);
    }
    __syncthreads();
    bf16x8 af[4], bfr[4];
#pragma unroll
    for (int mi = 0; mi < 4; mi++)
      af[mi] = *(const bf16x8*)(As + (wrow*64 + mi*16 + l16)*BK + quad*8);
#pragma unroll
    for (int ni = 0; ni < 4; ni++)
      bfr[ni] = *(const bf16x8*)(Bs + (wcol*64 + ni*16 + l16)*BK + quad*8);
#pragma unroll
    for (int mi = 0; mi < 4; mi++)
#pragma unroll
      for (int ni = 0; ni < 4; ni++)
        acc[mi][ni] = __builtin_amdgcn_mfma_f32_16x16x32_bf16(af[mi], bfr[ni], acc[mi][ni], 0, 0, 0);
    __syncthreads();
  }
#pragma unroll
  for (int mi = 0; mi < 4; mi++)
#pragma unroll
    for (int ni = 0; ni < 4; ni++){
      const int col = n0 + wcol*64 + ni*16 + l16;
#pragma unroll
      for (int r = 0; r < 4; r++){
        const int row = m0 + wrow*64 + mi*16 + quad*4 + r;
        if constexpr (F32OUT)
          ((float*)Cv)[(size_t)row*N + col] = acc[mi][ni][r];
        else
          ((u16*)Cv)[(size_t)row*N + col] = f2bf(acc[mi][ni][r]);
      }
    }
}

// V^T pre-transpose: VT[(b*8+hk)*64 + d][s] = QKV[b*2048+s][2560 + hk*64 + d]
__global__ __launch_bounds__(256)
void vtrans(const u16* __restrict__ QKV, u16* __restrict__ VT){
  __shared__ u16 Ls[64*72];
  const int tid = threadIdx.x;
  const int st = blockIdx.x, hk = blockIdx.y, b = blockIdx.z;
  const size_t rb = (size_t)b * SEQ;
#pragma unroll
  for (int t = 0; t < 2; t++){
    const int task = t*256 + tid;
    const int r = task >> 3, c = task & 7;
    *(uint4*)(Ls + r*72 + c*8) =
        *(const uint4*)(QKV + (rb + st*64 + r)*QKV_DIM + 2560 + hk*HEAD_DIM + c*8);
  }
  __syncthreads();
  u16* vt_g = VT + ((size_t)(b*8 + hk) * 64) * SEQ;
#pragma unroll
  for (int t = 0; t < 2; t++){
    const int task = t*256 + tid;
    const int d = task >> 3, sc = task & 7;
    union { u16 h[8]; uint4 v; } tmp;
#pragma unroll
    for (int e = 0; e < 8; e++) tmp.h[e] = Ls[(sc*8 + e)*72 + d];
    *(uint4*)(vt_g + (size_t)d*SEQ + st*64 + sc*8) = tmp.v;
  }
}

// R5's attn with ONE change: V^T staged from pre-transposed global buffer
// (uint4 in / uint4 out, same pattern as K staging) instead of scalar scatter.
__global__ __launch_bounds__(256)
void attn(const u16* __restrict__ Q, const u16* __restrict__ Kp,
          const u16* __restrict__ VT, u16* __restrict__ O, int qs, int ks){
  constexpr int KP = 72;
  __shared__ __attribute__((aligned(16))) u16 Ks[64*KP];
  __shared__ __attribute__((aligned(16))) u16 Vt[64*KP];
  __shared__ __attribute__((aligned(16))) u16 Ps[4*16*KP];
  const int tid = threadIdx.x;
  const int wave = tid >> 6, lane = tid & 63, quad = lane >> 4, l16 = lane & 15;
  const int qt = blockIdx.x, h = blockIdx.y, b = blockIdx.z;
  const int hk = h >> 2;
  const size_t rb = (size_t)b * SEQ;
  const u16* vt_g = VT + ((size_t)(b*8 + hk) * 64) * SEQ;

  bf16x8 qf[2];
  {
    const u16* qp = Q + (rb + qt*64 + wave*16 + l16)*qs + h*HEAD_DIM;
    qf[0] = *(const bf16x8*)(qp + quad*8);
    qf[1] = *(const bf16x8*)(qp + 32 + quad*8);
  }
  const f32x4 zero = {0.f, 0.f, 0.f, 0.f};
  f32x4 oacc[4];
#pragma unroll
  for (int i = 0; i < 4; i++) oacc[i] = zero;
  float m_i[4] = {-INFINITY, -INFINITY, -INFINITY, -INFINITY};
  float l_i[4] = {0.f, 0.f, 0.f, 0.f};
  u16* Pw = Ps + wave*16*KP;

  for (int j = 0; j <= qt; ++j){
    {
      const int r = tid >> 2, s = tid & 3;
      const u16* kg = Kp + (rb + j*64 + r)*ks + hk*HEAD_DIM;
      *(uint4*)(Ks + r*KP + s*8)     = *(const uint4*)(kg + s*8);
      *(uint4*)(Ks + r*KP + (s+4)*8) = *(const uint4*)(kg + (s+4)*8);
    }
    {  // V^T staging: rows = d (0..63), cols = 64 keys of this tile
      const int d = tid >> 2, s = tid & 3;
      const u16* vg = vt_g + (size_t)d*SEQ + j*64;
      *(uint4*)(Vt + d*KP + s*8)     = *(const uint4*)(vg + s*8);
      *(uint4*)(Vt + d*KP + (s+4)*8) = *(const uint4*)(vg + (s+4)*8);
    }
    __syncthreads();

    f32x4 st[4];
#pragma unroll
    for (int ni = 0; ni < 4; ni++){
      f32x4 s = zero;
#pragma unroll
      for (int ss = 0; ss < 2; ss++){
        bf16x8 kf = *(const bf16x8*)(Ks + (ni*16 + l16)*KP + ss*32 + quad*8);
        s = __builtin_amdgcn_mfma_f32_16x16x32_bf16(qf[ss], kf, s, 0, 0, 0);
      }
#pragma unroll
      for (int r = 0; r < 4; r++) st[ni][r] = s[r] * 0.125f;
    }
    if (j == qt){
#pragma unroll
      for (int ni = 0; ni < 4; ni++){
        const int col = ni*16 + l16;
#pragma unroll
        for (int r = 0; r < 4; r++)
          if (col > wave*16 + quad*4 + r) st[ni][r] = -INFINITY;
      }
    }
    float alpha[4];
#pragma unroll
    for (int r = 0; r < 4; r++){
      float mx = fmaxf(fmaxf(st[0][r], st[1][r]), fmaxf(st[2][r], st[3][r]));
      mx = fmaxf(mx, __shfl_xor(mx, 1));
      mx = fmaxf(mx, __shfl_xor(mx, 2));
      mx = fmaxf(mx, __shfl_xor(mx, 4));
      mx = fmaxf(mx, __shfl_xor(mx, 8));
      const float mn = fmaxf(m_i[r], mx);
      alpha[r] = __expf(m_i[r] - mn);
      float ps = 0.f;
#pragma unroll
      for (int ni = 0; ni < 4; ni++){
        const float p = __expf(st[ni][r] - mn);
        st[ni][r] = p;
        ps += p;
      }
      ps += __shfl_xor(ps, 1);
      ps += __shfl_xor(ps, 2);
      ps += __shfl_xor(ps, 4);
      ps += __shfl_xor(ps, 8);
      l_i[r] = l_i[r]*alpha[r] + ps;
      m_i[r] = mn;
    }
#pragma unroll
    for (int ci = 0; ci < 4; ci++)
#pragma unroll
      for (int r = 0; r < 4; r++) oacc[ci][r] *= alpha[r];
#pragma unroll
    for (int ni = 0; ni < 4; ni++)
#pragma unroll
      for (int r = 0; r < 4; r++)
        Pw[(quad*4 + r)*KP + ni*16 + l16] = f2bf(st[ni][r]);
    __asm__ volatile("s_waitcnt lgkmcnt(0)" ::: "memory");
#pragma unroll
    for (int ss = 0; ss < 2; ss++){
      bf16x8 pf = *(const bf16x8*)(Pw + l16*KP + ss*32 + quad*8);
#pragma unroll
      for (int ci = 0; ci < 4; ci++){
        bf16x8 vf = *(const bf16x8*)(Vt + (ci*16 + l16)*KP + ss*32 + quad*8);
        oacc[ci] = __builtin_amdgcn_mfma_f32_16x16x32_bf16(pf, vf, oacc[ci], 0, 0, 0);
      }
    }
    __syncthreads();
  }
#pragma unroll
  for (int ci = 0; ci < 4; ci++)
#pragma unroll
    for (int r = 0; r < 4; r++){
      const size_t row = rb + qt*64 + wave*16 + quad*4 + r;
      O[row*D_MODEL + h*HEAD_DIM + ci*16 + l16] = f2bf(oacc[ci][r] / l_i[r]);
    }
}

extern "C" void kernel_launch(void* const* d_in, const int* in_sizes, int n_in,
                              void* d_out, int out_size, void* d_ws, size_t ws_size,
                              hipStream_t stream){
  const float* x  = (const float*)d_in[0];
  const float* Wq = (const float*)d_in[1];
  const float* Wk = (const float*)d_in[2];
  const float* Wv = (const float*)d_in[3];
  const float* Wo = (const float*)d_in[4];
  float* out = (float*)d_out;

  u16* xb   = (u16*)d_ws;                    // x / later attn-out  [4096,2048]
  u16* Wb   = xb + (size_t)MTOT*D_MODEL;     // fused weights [3072,2048]
  u16* VTb  = Wb + (size_t)QKV_DIM*D_MODEL;  // V^T [16*64, 2048] (own slot)
  u16* QKVb = (u16*)d_out;                   // QKV scratch [4096,3072] bf16

  const int nx  = MTOT*D_MODEL;
  const int nwq = D_MODEL*D_MODEL;
  const int nwk = 512*D_MODEL;

  cvt_bf16<<<nx/2048, 256, 0, stream>>>(x, xb, nx);
  cvt_bf16<<<nwq/2048, 256, 0, stream>>>(Wq, Wb, nwq);
  cvt_bf16<<<nwk/2048, 256, 0, stream>>>(Wk, Wb + (size_t)D_MODEL*D_MODEL, nwk);
  cvt_bf16<<<nwk/2048, 256, 0, stream>>>(Wv, Wb + (size_t)2560*D_MODEL, nwk);
  gemm_bt<false><<<dim3(QKV_DIM/128, MTOT/128), 256, 0, stream>>>(xb, Wb, QKVb, MTOT, QKV_DIM, D_MODEL);
  vtrans<<<dim3(SEQ/64, 8, 2), 256, 0, stream>>>(QKVb, VTb);
  attn<<<dim3(SEQ/64, NUM_HEADS, 2), 256, 0, stream>>>(
      QKVb, QKVb + D_MODEL, VTb, xb, QKV_DIM, QKV_DIM);
  cvt_bf16<<<nwq/2048, 256, 0, stream>>>(Wo, Wb, nwq);
  gemm_bt<true><<<dim3(D_MODEL/128, MTOT/128), 256, 0, stream>>>(xb, Wb, (void*)out, MTOT, D_MODEL, D_MODEL);
}